// Round 4
// baseline (153.949 us; speedup 1.0000x reference)
//
#include <hip/hip_runtime.h>

// Problem constants (fixed by setup_inputs).
constexpr int Bn = 512;               // batch rows
constexpr int Ln = 512;               // sequence length
constexpr int Fn = 64;                // feature dim
constexpr int Vn = 20000;             // num_nodes (vocab)
constexpr int HWORDS = (Vn + 2) / 3;  // 10-bit-packed histogram words (3 counts/u32)
constexpr int BL = Bn * Ln;           // positions per channel = 262144 = 2^18
constexpr int TBLK = 129;             // table-role blocks (4 v-values each, 513 total)

typedef float vfloat4 __attribute__((ext_vector_type(4)));  // native vec for nt store

__device__ __forceinline__ unsigned hist_get(const unsigned* __restrict__ h, int v) {
    const int w = v / 3;
    const int f = v - w * 3;
    return (h[w] >> (10 * f)) & 0x3FFu;
}

// Fused prep: blocks [0,TBLK) build the 513x64 MLP lookup table
//   table[v][j] = sum_i relu(v*W1[i]+b1[i]) * W2[i][j] + b2[j]
// blocks [TBLK, TBLK+Bn) build per-row packed histograms and emit per-position
// packed counts: counts[a*BL + b*L + l] = c_in_src | c_in_dst<<16 (0 if id==0).
__global__ __launch_bounds__(256) void prep_kernel(
    const int* __restrict__ src_ids,
    const int* __restrict__ dst_ids,
    const float* __restrict__ W1,
    const float* __restrict__ b1,
    const float* __restrict__ W2,
    const float* __restrict__ b2,
    float* __restrict__ table,
    unsigned* __restrict__ counts) {
    __shared__ unsigned sm[2 * HWORDS];  // 53.3 KB; table role aliases 1 KB of it
    const int tid = threadIdx.x;

    if (blockIdx.x < TBLK) {
        // ---- table role: 4 count-values per block ----
        float* h = (float*)sm;           // h[sub][j], 4x64 floats
        const int sub = tid >> 6;        // 0..3
        const int j = tid & 63;
        const int v = blockIdx.x * 4 + sub;
        const bool live = (v <= 512);
        h[sub * Fn + j] = live ? fmaxf((float)v * W1[j] + b1[j], 0.0f) : 0.0f;
        __syncthreads();
        if (live) {
            float acc = b2[j];
            const float* hv = h + sub * Fn;
#pragma unroll
            for (int i = 0; i < Fn; ++i)
                acc = fmaf(hv[i], W2[i * Fn + j], acc);  // W2 column read coalesced in j
            table[v * Fn + j] = acc;
        }
        return;
    }

    // ---- histogram role: one batch row per block ----
    unsigned* hs = sm;
    unsigned* hd = sm + HWORDS;
    const int b = blockIdx.x - TBLK;

    for (int i = tid; i < 2 * HWORDS; i += 256) sm[i] = 0u;
    __syncthreads();

    const int* __restrict__ srow = src_ids + b * Ln;
    const int* __restrict__ drow = dst_ids + b * Ln;

    // Ln == 512 == 2*blockDim: each thread owns positions tid and tid+256.
    const int s0 = srow[tid], s1 = srow[tid + 256];
    const int d0 = drow[tid], d1 = drow[tid + 256];
    {
        int w;
        w = s0 / 3; atomicAdd(&hs[w], 1u << (10 * (s0 - w * 3)));
        w = s1 / 3; atomicAdd(&hs[w], 1u << (10 * (s1 - w * 3)));
        w = d0 / 3; atomicAdd(&hd[w], 1u << (10 * (d0 - w * 3)));
        w = d1 / 3; atomicAdd(&hd[w], 1u << (10 * (d1 - w * 3)));
    }
    __syncthreads();

    const size_t base = (size_t)b * Ln;
#pragma unroll
    for (int k = 0; k < 2; ++k) {
        const int l = tid + k * 256;
        const int s = (k == 0) ? s0 : s1;
        const int d = (k == 0) ? d0 : d1;
        unsigned ws = 0u, wd = 0u;
        if (s != 0) ws = hist_get(hs, s) | (hist_get(hd, s) << 16);
        if (d != 0) wd = hist_get(hs, d) | (hist_get(hd, d) << 16);
        counts[base + l] = ws;
        counts[BL + base + l] = wd;
    }
}

// Expansion: one thread per output float4. Pure streaming-store bound.
// Table rows are L1-hot (counts are tiny ints); output stores bypass caches (nt).
__global__ __launch_bounds__(256) void expand_kernel(
    const unsigned* __restrict__ counts,
    const float* __restrict__ table,
    float* __restrict__ out) {
    const unsigned g = blockIdx.x * 256u + threadIdx.x;
    const unsigned r = g & 15u;
    const unsigned idx = g >> 4;              // channel*BL + position
    const unsigned w = counts[idx];           // broadcast within 16-thread group
    const unsigned c0 = w & 0xFFFFu;
    const unsigned c1 = w >> 16;
    const vfloat4* tp0 = (const vfloat4*)(table + c0 * Fn) + r;
    const vfloat4* tp1 = (const vfloat4*)(table + c1 * Fn) + r;
    const vfloat4 o = *tp0 + *tp1;
    __builtin_nontemporal_store(o, (vfloat4*)(out + (size_t)idx * Fn) + r);
}

extern "C" void kernel_launch(void* const* d_in, const int* in_sizes, int n_in,
                              void* d_out, int out_size, void* d_ws, size_t ws_size,
                              hipStream_t stream) {
    const int*   src_ids = (const int*)d_in[0];
    const int*   dst_ids = (const int*)d_in[1];
    const float* W1      = (const float*)d_in[2];
    const float* b1      = (const float*)d_in[3];
    const float* W2      = (const float*)d_in[4];
    const float* b2      = (const float*)d_in[5];
    // d_in[6] = num_nodes scalar (20000) — hardcoded as Vn.

    float*    table  = (float*)d_ws;                   // 513*64*4 = 131 KB
    unsigned* counts = (unsigned*)(table + 513 * Fn);  // 2*BL*4 = 2 MB

    prep_kernel<<<TBLK + Bn, 256, 0, stream>>>(src_ids, dst_ids, W1, b1, W2, b2,
                                               table, counts);
    // 2*BL positions * 16 float4-slots / 256 threads = 32768 blocks.
    expand_kernel<<<(2 * BL * 16) / 256, 256, 0, stream>>>(counts, table, (float*)d_out);
}